// Round 12
// baseline (43.766 us; speedup 1.0000x reference)
//
#include <hip/hip_runtime.h>
#include <hip/hip_bf16.h>
#include <math.h>

// Problem constants (fixed by setup_inputs)
static constexpr int Cc   = 16;   // C
static constexpr int COc  = 16;   // CO
static constexpr int Hh   = 4;    // heads
static constexpr int CPWc = 32;   // 2*C
static constexpr int NTH  = 256;  // block size
static constexpr int TFL  = 768;  // floats per packed 16-k tile (3 KB)

typedef __attribute__((ext_vector_type(8))) short bf16x8;   // 8 bf16 = 4 VGPR
typedef __attribute__((ext_vector_type(4))) float f32x4v;   // MFMA C/D

union F4 { float4 v; float f[4]; };

__device__ __forceinline__ short f2bf(float x) {
  __hip_bfloat16 h = __float2bfloat16(x);
  return *reinterpret_cast<short*>(&h);
}

// ---------------------------------------------------------------------------
// Kernel 1: per-row first-layer projections + packing (validated r11).
// k rows -> cP consumption-ordered packed tiles (dense lane*16B reads):
//   [  0,256): lane l=g*16+m -> cW[k=T*16+m][g*8 .. g*8+3]
//   [256,512): lane l        -> cW[k][g*8+4 .. g*8+7]
//   [512,640): lane l&31     -> cV[k][gg*8 .. gg*8+3]   (gg = g&1)
//   [640,768): lane l&31     -> cV[k][gg*8+4 .. gg*8+7]
// Block nRowBlocks packs w2/v2 MFMA B-fragments (v2f = 0.5*v2 duplicated
// into both K-halves; A duplicates hv -> exact).
// ---------------------------------------------------------------------------
__global__ __launch_bounds__(NTH) void ppa_precompute(
    const float* __restrict__ xq, const float* __restrict__ xk,
    const float* __restrict__ w1, const float* __restrict__ b1,
    const float* __restrict__ v1, const float* __restrict__ bv1,
    const float* __restrict__ w2, const float* __restrict__ v2,
    float* __restrict__ aW, float* __restrict__ aV,
    float* __restrict__ cP,
    ushort* __restrict__ w2f, ushort* __restrict__ v2f,
    int BN, int BK, int Nk, int nRowBlocks) {
  const int t = threadIdx.x;

  if (blockIdx.x == nRowBlocks) {  // packing block
    if (t < 64) {
      const int n = t & 15, g = t >> 4;
#pragma unroll
      for (int i = 0; i < 8; ++i) {
        const int k = g * 8 + i;
        w2f[t * 8 + i] = (n < Hh) ? (ushort)f2bf(w2[k * Hh + n]) : (ushort)0;
        v2f[t * 8 + i] = (ushort)f2bf(0.5f * v2[(k & 15) * COc + n]);
      }
    }
    return;
  }

  __shared__ float sw1[CPWc * CPWc];
  __shared__ float sv1[CPWc * COc];
  __shared__ float sb1[CPWc];
  __shared__ float sbv1[COc];
  for (int i = t; i < CPWc * CPWc; i += NTH) sw1[i] = w1[i];
  for (int i = t; i < CPWc * COc; i += NTH) sv1[i] = v1[i];
  if (t < CPWc) sb1[t] = b1[t];
  if (t < COc) sbv1[t] = bv1[t];
  __syncthreads();

  const int r = blockIdx.x * NTH + t;
  if (r >= BN + BK) return;
  const bool isQ = (r < BN);
  const int rr = isQ ? r : (r - BN);
  const float* src = isQ ? (xq + (size_t)rr * Cc) : (xk + (size_t)rr * Cc);

  float x[Cc];
#pragma unroll
  for (int i = 0; i < Cc; i += 4) {
    float4 v = *reinterpret_cast<const float4*>(src + i);
    x[i] = v.x; x[i + 1] = v.y; x[i + 2] = v.z; x[i + 3] = v.w;
  }

  if (isQ) {
#pragma unroll
    for (int j = 0; j < CPWc; ++j) {
      float acc = sb1[j];
#pragma unroll
      for (int i = 0; i < Cc; ++i)
        acc += x[i] * (sw1[i * CPWc + j] - sw1[(i + Cc) * CPWc + j]);
      aW[(size_t)rr * CPWc + j] = acc;
    }
#pragma unroll
    for (int j = 0; j < COc; ++j) {
      float acc = sbv1[j];
#pragma unroll
      for (int i = 0; i < Cc; ++i)
        acc += x[i] * (sv1[i * COc + j] - sv1[(i + Cc) * COc + j]);
      aV[(size_t)rr * COc + j] = acc;
    }
  } else {
    float cw[CPWc], cv[COc];
#pragma unroll
    for (int j = 0; j < CPWc; ++j) {
      float acc = 0.f;
#pragma unroll
      for (int i = 0; i < Cc; ++i) acc += x[i] * sw1[(i + Cc) * CPWc + j];
      cw[j] = acc;
    }
#pragma unroll
    for (int j = 0; j < COc; ++j) {
      float acc = 0.f;
#pragma unroll
      for (int i = 0; i < Cc; ++i) acc += x[i] * sv1[(i + Cc) * COc + j];
      cv[j] = acc;
    }
    const int bb = rr / Nk;
    const int kk = rr - bb * Nk;
    const int T = kk >> 4, mm = kk & 15;
    float* tp = cP + ((size_t)bb * (Nk >> 4) + T) * TFL;
#pragma unroll
    for (int g = 0; g < 4; ++g) {
      F4 w0, w1s;
#pragma unroll
      for (int i = 0; i < 4; ++i) { w0.f[i] = cw[g * 8 + i]; w1s.f[i] = cw[g * 8 + 4 + i]; }
      *reinterpret_cast<float4*>(tp + (g * 16 + mm) * 4) = w0.v;
      *reinterpret_cast<float4*>(tp + 256 + (g * 16 + mm) * 4) = w1s.v;
    }
#pragma unroll
    for (int gg = 0; gg < 2; ++gg) {
      F4 v0, v1s;
#pragma unroll
      for (int i = 0; i < 4; ++i) { v0.f[i] = cv[gg * 8 + i]; v1s.f[i] = cv[gg * 8 + 4 + i]; }
      *reinterpret_cast<float4*>(tp + 512 + (gg * 16 + mm) * 4) = v0.v;
      *reinterpret_cast<float4*>(tp + 640 + (gg * 16 + mm) * 4) = v1s.v;
    }
  }
}

// ---------------------------------------------------------------------------
// Kernel 2 (MFMA): one block per TWO consecutive (b,n) rows (same batch:
// N even), 4 waves, wave w owns tiles T = w*16+s. R12 change: each shared
// packed-tile load (c0/c1/d0/d1) now feeds BOTH rows' fragment builds and
// MFMAs -> L1/L2 bytes per row halve (r11 showed traffic ~ VALU cost;
// r11's layout fix proved the memory path is the lever). 2x ILP per wave
// offsets the occupancy drop (1024 blocks).
// Fragment math, p-shfl routing, bias-in-C, l-accum on m&3==0: validated
// r8-r11. Plain exp-sum softmax (logits ReLU'd >= 0). No launch-bounds cap
// (r2-r7 law: cap -> spill).
// ---------------------------------------------------------------------------
__global__ __launch_bounds__(NTH) void ppa_main_mfma(
    const float* __restrict__ aW, const float* __restrict__ aV,
    const float* __restrict__ cP,
    const ushort* __restrict__ w2f, const float* __restrict__ b2,
    const ushort* __restrict__ v2f, const float* __restrict__ bv2,
    float* __restrict__ out, int N, int Nk) {
  __shared__ float sro[4][2][COc];
  __shared__ float srl[4][2][Hh];

  const int t = threadIdx.x;
  const int lane = t & 63, w = t >> 6;
  const int m = lane & 15;
  const int g = lane >> 4;
  const int gg = g & 1;
  const int l31 = lane & 31;
  const int hh = m >> 2;
  const int psrc = (lane & 48) | hh;
  const int row0 = blockIdx.x * 2;
  const int b = row0 / N;

  // Loop-invariant per-lane data for both rows.
  float a0[8], a1[8], av0[8], av1[8];
#pragma unroll
  for (int r = 0; r < 2; ++r) {
    float* ar = r ? a1 : a0;
    float* vr = r ? av1 : av0;
    const float* aRow = aW + (size_t)(row0 + r) * CPWc + g * 8;
    const float* avRow = aV + (size_t)(row0 + r) * COc + gg * 8;
#pragma unroll
    for (int i = 0; i < 8; i += 4) {
      F4 v; v.v = *reinterpret_cast<const float4*>(aRow + i);
      ar[i] = v.f[0]; ar[i + 1] = v.f[1]; ar[i + 2] = v.f[2]; ar[i + 3] = v.f[3];
      F4 u; u.v = *reinterpret_cast<const float4*>(avRow + i);
      vr[i] = u.f[0]; vr[i + 1] = u.f[1]; vr[i + 2] = u.f[2]; vr[i + 3] = u.f[3];
    }
  }
  const bf16x8 wfrag = *reinterpret_cast<const bf16x8*>(w2f + lane * 8);
  const bf16x8 vfrag = *reinterpret_cast<const bf16x8*>(v2f + lane * 8);
  const float b2h = b2[m < Hh ? m : (Hh - 1)];
  const float bv2c = bv2[m];
  const f32x4v cbW = {b2h, b2h, b2h, b2h};
  const f32x4v cbV = {bv2c, bv2c, bv2c, bv2c};

  float oa0 = 0.f, la0 = 0.f, oa1 = 0.f, la1 = 0.f;

  const float* tb = cP + ((size_t)b * (Nk >> 4) + (size_t)w * 16) * TFL;

  // ---- software pipeline: prefetch tile s+1 while processing tile s.
  F4 c0, c1, d0, d1;
  c0.v = *reinterpret_cast<const float4*>(tb + lane * 4);
  c1.v = *reinterpret_cast<const float4*>(tb + 256 + lane * 4);
  d0.v = *reinterpret_cast<const float4*>(tb + 512 + l31 * 4);
  d1.v = *reinterpret_cast<const float4*>(tb + 640 + l31 * 4);

#pragma unroll
  for (int s = 0; s < 16; ++s) {
    F4 n0 = {}, n1 = {}, e0 = {}, e1 = {};
    if (s < 15) {
      const float* nb = tb + (size_t)(s + 1) * TFL;
      n0.v = *reinterpret_cast<const float4*>(nb + lane * 4);
      n1.v = *reinterpret_cast<const float4*>(nb + 256 + lane * 4);
      e0.v = *reinterpret_cast<const float4*>(nb + 512 + l31 * 4);
      e1.v = *reinterpret_cast<const float4*>(nb + 640 + l31 * 4);
    }

    // ---- row 0 logits
    const bf16x8 afW0 = {
      f2bf(fmaxf(a0[0] + c0.f[0], 0.f)), f2bf(fmaxf(a0[1] + c0.f[1], 0.f)),
      f2bf(fmaxf(a0[2] + c0.f[2], 0.f)), f2bf(fmaxf(a0[3] + c0.f[3], 0.f)),
      f2bf(fmaxf(a0[4] + c1.f[0], 0.f)), f2bf(fmaxf(a0[5] + c1.f[1], 0.f)),
      f2bf(fmaxf(a0[6] + c1.f[2], 0.f)), f2bf(fmaxf(a0[7] + c1.f[3], 0.f)),
    };
    const f32x4v lg0 =
        __builtin_amdgcn_mfma_f32_16x16x32_bf16(afW0, wfrag, cbW, 0, 0, 0);
    // ---- row 1 logits
    const bf16x8 afW1 = {
      f2bf(fmaxf(a1[0] + c0.f[0], 0.f)), f2bf(fmaxf(a1[1] + c0.f[1], 0.f)),
      f2bf(fmaxf(a1[2] + c0.f[2], 0.f)), f2bf(fmaxf(a1[3] + c0.f[3], 0.f)),
      f2bf(fmaxf(a1[4] + c1.f[0], 0.f)), f2bf(fmaxf(a1[5] + c1.f[1], 0.f)),
      f2bf(fmaxf(a1[6] + c1.f[2], 0.f)), f2bf(fmaxf(a1[7] + c1.f[3], 0.f)),
    };
    const f32x4v lg1 =
        __builtin_amdgcn_mfma_f32_16x16x32_bf16(afW1, wfrag, cbW, 0, 0, 0);

    const float p00 = __expf(fmaxf(lg0[0], 0.f));
    const float p01 = __expf(fmaxf(lg0[1], 0.f));
    const float p02 = __expf(fmaxf(lg0[2], 0.f));
    const float p03 = __expf(fmaxf(lg0[3], 0.f));
    const float p10 = __expf(fmaxf(lg1[0], 0.f));
    const float p11 = __expf(fmaxf(lg1[1], 0.f));
    const float p12 = __expf(fmaxf(lg1[2], 0.f));
    const float p13 = __expf(fmaxf(lg1[3], 0.f));

    const float q00 = __shfl(p00, psrc);
    const float q01 = __shfl(p01, psrc);
    const float q02 = __shfl(p02, psrc);
    const float q03 = __shfl(p03, psrc);
    const float q10 = __shfl(p10, psrc);
    const float q11 = __shfl(p11, psrc);
    const float q12 = __shfl(p12, psrc);
    const float q13 = __shfl(p13, psrc);
    if ((m & 3) == 0) {
      la0 += (q00 + q01) + (q02 + q03);
      la1 += (q10 + q11) + (q12 + q13);
    }

    // ---- row 0 values
    const bf16x8 afV0 = {
      f2bf(fmaxf(av0[0] + d0.f[0], 0.f)), f2bf(fmaxf(av0[1] + d0.f[1], 0.f)),
      f2bf(fmaxf(av0[2] + d0.f[2], 0.f)), f2bf(fmaxf(av0[3] + d0.f[3], 0.f)),
      f2bf(fmaxf(av0[4] + d1.f[0], 0.f)), f2bf(fmaxf(av0[5] + d1.f[1], 0.f)),
      f2bf(fmaxf(av0[6] + d1.f[2], 0.f)), f2bf(fmaxf(av0[7] + d1.f[3], 0.f)),
    };
    const f32x4v vD0 =
        __builtin_amdgcn_mfma_f32_16x16x32_bf16(afV0, vfrag, cbV, 0, 0, 0);
    // ---- row 1 values
    const bf16x8 afV1 = {
      f2bf(fmaxf(av1[0] + d0.f[0], 0.f)), f2bf(fmaxf(av1[1] + d0.f[1], 0.f)),
      f2bf(fmaxf(av1[2] + d0.f[2], 0.f)), f2bf(fmaxf(av1[3] + d0.f[3], 0.f)),
      f2bf(fmaxf(av1[4] + d1.f[0], 0.f)), f2bf(fmaxf(av1[5] + d1.f[1], 0.f)),
      f2bf(fmaxf(av1[6] + d1.f[2], 0.f)), f2bf(fmaxf(av1[7] + d1.f[3], 0.f)),
    };
    const f32x4v vD1 =
        __builtin_amdgcn_mfma_f32_16x16x32_bf16(afV1, vfrag, cbV, 0, 0, 0);

    oa0 += q00 * fmaxf(vD0[0], 0.f);
    oa0 += q01 * fmaxf(vD0[1], 0.f);
    oa0 += q02 * fmaxf(vD0[2], 0.f);
    oa0 += q03 * fmaxf(vD0[3], 0.f);
    oa1 += q10 * fmaxf(vD1[0], 0.f);
    oa1 += q11 * fmaxf(vD1[1], 0.f);
    oa1 += q12 * fmaxf(vD1[2], 0.f);
    oa1 += q13 * fmaxf(vD1[3], 0.f);

    c0 = n0; c1 = n1; d0 = e0; d1 = e1;
  }

  // ---- reduce over g-groups (xor 16/32 preserves m), then across waves.
  oa0 += __shfl_xor(oa0, 16);
  oa0 += __shfl_xor(oa0, 32);
  oa1 += __shfl_xor(oa1, 16);
  oa1 += __shfl_xor(oa1, 32);
  la0 += __shfl_xor(la0, 16);
  la0 += __shfl_xor(la0, 32);
  la1 += __shfl_xor(la1, 16);
  la1 += __shfl_xor(la1, 32);
  if (lane < COc) { sro[w][0][m] = oa0; sro[w][1][m] = oa1; }
  if (lane < COc && (lane & 3) == 0) {
    srl[w][0][lane >> 2] = la0;
    srl[w][1][lane >> 2] = la1;
  }
  __syncthreads();

  if (t < 2 * COc) {
    const int r = t >> 4, c = t & 15, h = c >> 2;
    const float osum = (sro[0][r][c] + sro[1][r][c]) + (sro[2][r][c] + sro[3][r][c]);
    const float lsum = (srl[0][r][h] + srl[1][r][h]) + (srl[2][r][h] + srl[3][r][h]);
    out[(size_t)(row0 + r) * COc + c] = osum / lsum;
  }
}

// ---------------------------------------------------------------------------
extern "C" void kernel_launch(void* const* d_in, const int* in_sizes, int n_in,
                              void* d_out, int out_size, void* d_ws, size_t ws_size,
                              hipStream_t stream) {
  const float* xq  = (const float*)d_in[0];
  const float* xk  = (const float*)d_in[1];
  const float* w1  = (const float*)d_in[2];
  const float* b1  = (const float*)d_in[3];
  const float* w2  = (const float*)d_in[4];
  const float* b2  = (const float*)d_in[5];
  const float* v1  = (const float*)d_in[6];
  const float* bv1 = (const float*)d_in[7];
  const float* v2  = (const float*)d_in[8];
  const float* bv2 = (const float*)d_in[9];
  float* out = (float*)d_out;

  const int BN = in_sizes[0] / Cc;  // B*N  = 2048
  const int BK = in_sizes[1] / Cc;  // B*Nk = 2048
  const int B = 2;                  // fixed by setup_inputs
  const int N = BN / B;
  const int Nk = BK / B;

  float* ws = (float*)d_ws;
  float* aW = ws;                              // BN*32
  float* aV = aW + (size_t)BN * CPWc;          // BN*16
  float* cP = aV + (size_t)BN * COc;           // BK*48 (packed tiles)
  ushort* w2f = (ushort*)(cP + (size_t)BK * 48);  // 64*8 ushort
  ushort* v2f = w2f + 64 * 8;                     // 64*8 ushort

  const int totalRows = BN + BK;
  const int pgrid = (totalRows + NTH - 1) / NTH;
  ppa_precompute<<<pgrid + 1, NTH, 0, stream>>>(
      xq, xk, w1, b1, v1, bv1, w2, v2,
      aW, aV, cP, w2f, v2f, BN, BK, Nk, pgrid);
  ppa_main_mfma<<<BN / 2, NTH, 0, stream>>>(aW, aV, cP, w2f, b2, v2f, bv2,
                                            out, N, Nk);
}

// Round 13
// 30.293 us; speedup vs baseline: 1.4448x; 1.4448x over previous
//
#include <hip/hip_runtime.h>
#include <hip/hip_bf16.h>
#include <math.h>

// Problem constants (fixed by setup_inputs)
static constexpr int Cc   = 16;   // C
static constexpr int COc  = 16;   // CO
static constexpr int Hh   = 4;    // heads
static constexpr int CPWc = 32;   // 2*C
static constexpr int NTH  = 256;  // precompute block size
static constexpr int MTH  = 512;  // main block size (8 waves, 2 rows)
static constexpr int TFL  = 768;  // floats per packed 16-k tile (3 KB)

typedef __attribute__((ext_vector_type(8))) short bf16x8;   // 8 bf16 = 4 VGPR
typedef __attribute__((ext_vector_type(4))) float f32x4v;   // MFMA C/D

union F4 { float4 v; float f[4]; };

__device__ __forceinline__ short f2bf(float x) {
  __hip_bfloat16 h = __float2bfloat16(x);
  return *reinterpret_cast<short*>(&h);
}

// ---------------------------------------------------------------------------
// Kernel 1: per-row first-layer projections + packing, 4 THREADS PER ROW
// (r13: widen parallelism; the 16-block r11 version was a ~8us latency-bound
// serial prefix). Thread (row r, sub=t&3) computes cw[sub*8..+8) and
// cv[sub*4..+4) (k rows) or the matching aW/aV slices (q rows).
// cP packed layout (validated r11):
//   [  0,256): lane l=g*16+m -> cW[k=T*16+m][g*8 .. g*8+3]
//   [256,512): lane l        -> cW[k][g*8+4 .. g*8+7]
//   [512,640): lane l&31     -> cV[k][gg*8 .. gg*8+3]   (gg = g&1)
//   [640,768): lane l&31     -> cV[k][gg*8+4 .. gg*8+7]
// Block nRowBlocks packs w2/v2 MFMA B-fragments (v2f = 0.5*v2 duplicated
// into both K-halves; A duplicates hv -> exact; validated r10-r12).
// ---------------------------------------------------------------------------
__global__ __launch_bounds__(NTH) void ppa_precompute(
    const float* __restrict__ xq, const float* __restrict__ xk,
    const float* __restrict__ w1, const float* __restrict__ b1,
    const float* __restrict__ v1, const float* __restrict__ bv1,
    const float* __restrict__ w2, const float* __restrict__ v2,
    float* __restrict__ aW, float* __restrict__ aV,
    float* __restrict__ cP,
    ushort* __restrict__ w2f, ushort* __restrict__ v2f,
    int BN, int BK, int Nk, int nRowBlocks) {
  const int t = threadIdx.x;

  if (blockIdx.x == nRowBlocks) {  // packing block
    if (t < 64) {
      const int n = t & 15, g = t >> 4;
#pragma unroll
      for (int i = 0; i < 8; ++i) {
        const int k = g * 8 + i;
        w2f[t * 8 + i] = (n < Hh) ? (ushort)f2bf(w2[k * Hh + n]) : (ushort)0;
        v2f[t * 8 + i] = (ushort)f2bf(0.5f * v2[(k & 15) * COc + n]);
      }
    }
    return;
  }

  __shared__ float sw1[CPWc * CPWc];
  __shared__ float sv1[CPWc * COc];
  __shared__ float sb1[CPWc];
  __shared__ float sbv1[COc];
  for (int i = t; i < CPWc * CPWc; i += NTH) sw1[i] = w1[i];
  for (int i = t; i < CPWc * COc; i += NTH) sv1[i] = v1[i];
  if (t < CPWc) sb1[t] = b1[t];
  if (t < COc) sbv1[t] = bv1[t];
  __syncthreads();

  const int r = blockIdx.x * 64 + (t >> 2);
  const int sub = t & 3;
  if (r >= BN + BK) return;
  const bool isQ = (r < BN);
  const int rr = isQ ? r : (r - BN);
  const float* src = isQ ? (xq + (size_t)rr * Cc) : (xk + (size_t)rr * Cc);

  float x[Cc];
#pragma unroll
  for (int i = 0; i < Cc; i += 4) {
    float4 v = *reinterpret_cast<const float4*>(src + i);
    x[i] = v.x; x[i + 1] = v.y; x[i + 2] = v.z; x[i + 3] = v.w;
  }

  if (isQ) {
    F4 o0, o1, ov;
#pragma unroll
    for (int jj = 0; jj < 8; ++jj) {
      const int j = sub * 8 + jj;
      float acc = sb1[j];
#pragma unroll
      for (int i = 0; i < Cc; ++i)
        acc += x[i] * (sw1[i * CPWc + j] - sw1[(i + Cc) * CPWc + j]);
      if (jj < 4) o0.f[jj] = acc; else o1.f[jj - 4] = acc;
    }
#pragma unroll
    for (int jj = 0; jj < 4; ++jj) {
      const int j = sub * 4 + jj;
      float acc = sbv1[j];
#pragma unroll
      for (int i = 0; i < Cc; ++i)
        acc += x[i] * (sv1[i * COc + j] - sv1[(i + Cc) * COc + j]);
      ov.f[jj] = acc;
    }
    float* ap = aW + (size_t)rr * CPWc + sub * 8;
    *reinterpret_cast<float4*>(ap) = o0.v;
    *reinterpret_cast<float4*>(ap + 4) = o1.v;
    *reinterpret_cast<float4*>(aV + (size_t)rr * COc + sub * 4) = ov.v;
  } else {
    F4 w0, w1s, cv4;
#pragma unroll
    for (int jj = 0; jj < 8; ++jj) {
      const int j = sub * 8 + jj;
      float acc = 0.f;
#pragma unroll
      for (int i = 0; i < Cc; ++i) acc += x[i] * sw1[(i + Cc) * CPWc + j];
      if (jj < 4) w0.f[jj] = acc; else w1s.f[jj - 4] = acc;
    }
#pragma unroll
    for (int jj = 0; jj < 4; ++jj) {
      const int j = sub * 4 + jj;
      float acc = 0.f;
#pragma unroll
      for (int i = 0; i < Cc; ++i) acc += x[i] * sv1[(i + Cc) * COc + j];
      cv4.f[jj] = acc;
    }
    const int bb = rr / Nk;
    const int kk = rr - bb * Nk;
    const int T = kk >> 4, mm = kk & 15;
    float* tp = cP + ((size_t)bb * (Nk >> 4) + T) * TFL;
    const int g = sub;                 // cW octet group == sub
    *reinterpret_cast<float4*>(tp + (g * 16 + mm) * 4) = w0.v;
    *reinterpret_cast<float4*>(tp + 256 + (g * 16 + mm) * 4) = w1s.v;
    const int gg = sub >> 1, half = sub & 1;  // cv[sub*4..+4)
    *reinterpret_cast<float4*>(tp + 512 + half * 128 + (gg * 16 + mm) * 4) = cv4.v;
  }
}

// ---------------------------------------------------------------------------
// Kernel 2 (MFMA): one block per TWO consecutive (b,n) rows, 512 threads =
// 8 waves. Wave w: row = row0 + (w>>2), k-quarter q = w&3. Waves w and w+4
// read the SAME packed tile sequence -> the second reader hits L1 (r13:
// traffic halves with ZERO extra registers/VALU -- the fix for r12's
// regression, which paid for sharing in per-wave registers and ILP).
// Per-wave body is byte-identical to r11 (proven 33us). Fragment math,
// p-shfl routing, bias-in-C, l-accum on m&3==0: validated r8-r11. Plain
// exp-sum softmax (logits ReLU'd >= 0). No launch-bounds cap (r2-r7 law).
// ---------------------------------------------------------------------------
__global__ __launch_bounds__(MTH) void ppa_main_mfma(
    const float* __restrict__ aW, const float* __restrict__ aV,
    const float* __restrict__ cP,
    const ushort* __restrict__ w2f, const float* __restrict__ b2,
    const ushort* __restrict__ v2f, const float* __restrict__ bv2,
    float* __restrict__ out, int N, int Nk) {
  __shared__ float sro[8][COc];
  __shared__ float srl[8][Hh];

  const int t = threadIdx.x;
  const int lane = t & 63, w = t >> 6;
  const int q = w & 3;        // k-quarter
  const int m = lane & 15;
  const int g = lane >> 4;
  const int gg = g & 1;
  const int l31 = lane & 31;
  const int hh = m >> 2;
  const int psrc = (lane & 48) | hh;
  const int row0 = blockIdx.x * 2;
  const int row = row0 + (w >> 2);
  const int b = row0 / N;     // both rows in same batch (N even)

  // Loop-invariant per-lane data.
  float a_reg[8];
  {
    const float* aRow = aW + (size_t)row * CPWc + g * 8;
#pragma unroll
    for (int i = 0; i < 8; i += 4) {
      F4 v; v.v = *reinterpret_cast<const float4*>(aRow + i);
      a_reg[i] = v.f[0]; a_reg[i + 1] = v.f[1];
      a_reg[i + 2] = v.f[2]; a_reg[i + 3] = v.f[3];
    }
  }
  float av_reg[8];
  {
    const float* avRow = aV + (size_t)row * COc + gg * 8;
#pragma unroll
    for (int i = 0; i < 8; i += 4) {
      F4 v; v.v = *reinterpret_cast<const float4*>(avRow + i);
      av_reg[i] = v.f[0]; av_reg[i + 1] = v.f[1];
      av_reg[i + 2] = v.f[2]; av_reg[i + 3] = v.f[3];
    }
  }
  const bf16x8 wfrag = *reinterpret_cast<const bf16x8*>(w2f + lane * 8);
  const bf16x8 vfrag = *reinterpret_cast<const bf16x8*>(v2f + lane * 8);
  const float b2h = b2[m < Hh ? m : (Hh - 1)];
  const float bv2c = bv2[m];
  const f32x4v cbW = {b2h, b2h, b2h, b2h};
  const f32x4v cbV = {bv2c, bv2c, bv2c, bv2c};

  float o_acc = 0.f, l_acc = 0.f;

  // Wave's packed tile base: tiles T = q*16 + s.
  const float* tb = cP + ((size_t)b * (Nk >> 4) + (size_t)q * 16) * TFL;

  // ---- software pipeline: prefetch tile s+1 while processing tile s.
  F4 c0, c1, d0, d1;
  c0.v = *reinterpret_cast<const float4*>(tb + lane * 4);
  c1.v = *reinterpret_cast<const float4*>(tb + 256 + lane * 4);
  d0.v = *reinterpret_cast<const float4*>(tb + 512 + l31 * 4);
  d1.v = *reinterpret_cast<const float4*>(tb + 640 + l31 * 4);

#pragma unroll
  for (int s = 0; s < 16; ++s) {
    F4 n0 = {}, n1 = {}, e0 = {}, e1 = {};
    if (s < 15) {
      const float* nb = tb + (size_t)(s + 1) * TFL;
      n0.v = *reinterpret_cast<const float4*>(nb + lane * 4);
      n1.v = *reinterpret_cast<const float4*>(nb + 256 + lane * 4);
      e0.v = *reinterpret_cast<const float4*>(nb + 512 + l31 * 4);
      e1.v = *reinterpret_cast<const float4*>(nb + 640 + l31 * 4);
    }

    // ---- logits tile: A = hw = relu(a + cW)[m][g*8..g*8+7]; C = b2.
    const bf16x8 afW = {
      f2bf(fmaxf(a_reg[0] + c0.f[0], 0.f)),
      f2bf(fmaxf(a_reg[1] + c0.f[1], 0.f)),
      f2bf(fmaxf(a_reg[2] + c0.f[2], 0.f)),
      f2bf(fmaxf(a_reg[3] + c0.f[3], 0.f)),
      f2bf(fmaxf(a_reg[4] + c1.f[0], 0.f)),
      f2bf(fmaxf(a_reg[5] + c1.f[1], 0.f)),
      f2bf(fmaxf(a_reg[6] + c1.f[2], 0.f)),
      f2bf(fmaxf(a_reg[7] + c1.f[3], 0.f)),
    };
    const f32x4v lgD =
        __builtin_amdgcn_mfma_f32_16x16x32_bf16(afW, wfrag, cbW, 0, 0, 0);

    const float p0 = __expf(fmaxf(lgD[0], 0.f));
    const float p1 = __expf(fmaxf(lgD[1], 0.f));
    const float p2 = __expf(fmaxf(lgD[2], 0.f));
    const float p3 = __expf(fmaxf(lgD[3], 0.f));

    const float q0 = __shfl(p0, psrc);
    const float q1 = __shfl(p1, psrc);
    const float q2 = __shfl(p2, psrc);
    const float q3 = __shfl(p3, psrc);
    if ((m & 3) == 0) l_acc += (q0 + q1) + (q2 + q3);

    // ---- val tile: A = hv duplicated into both K-halves (v2f = 0.5*v2 in
    //      both halves -> exact); C = bv2.
    const bf16x8 afV = {
      f2bf(fmaxf(av_reg[0] + d0.f[0], 0.f)),
      f2bf(fmaxf(av_reg[1] + d0.f[1], 0.f)),
      f2bf(fmaxf(av_reg[2] + d0.f[2], 0.f)),
      f2bf(fmaxf(av_reg[3] + d0.f[3], 0.f)),
      f2bf(fmaxf(av_reg[4] + d1.f[0], 0.f)),
      f2bf(fmaxf(av_reg[5] + d1.f[1], 0.f)),
      f2bf(fmaxf(av_reg[6] + d1.f[2], 0.f)),
      f2bf(fmaxf(av_reg[7] + d1.f[3], 0.f)),
    };
    const f32x4v vD =
        __builtin_amdgcn_mfma_f32_16x16x32_bf16(afV, vfrag, cbV, 0, 0, 0);

    o_acc += q0 * fmaxf(vD[0], 0.f);
    o_acc += q1 * fmaxf(vD[1], 0.f);
    o_acc += q2 * fmaxf(vD[2], 0.f);
    o_acc += q3 * fmaxf(vD[3], 0.f);

    c0 = n0; c1 = n1; d0 = e0; d1 = e1;
  }

  // ---- reduce over g-groups (xor 16/32 preserves m), then across waves.
  o_acc += __shfl_xor(o_acc, 16);
  o_acc += __shfl_xor(o_acc, 32);
  l_acc += __shfl_xor(l_acc, 16);
  l_acc += __shfl_xor(l_acc, 32);
  if (lane < COc) sro[w][m] = o_acc;
  if (lane < COc && (lane & 3) == 0) srl[w][lane >> 2] = l_acc;
  __syncthreads();

  if (t < 2 * COc) {
    const int r = t >> 4, c = t & 15, h = c >> 2;
    const int wb = r * 4;
    const float osum = (sro[wb][c] + sro[wb + 1][c]) +
                       (sro[wb + 2][c] + sro[wb + 3][c]);
    const float lsum = (srl[wb][h] + srl[wb + 1][h]) +
                       (srl[wb + 2][h] + srl[wb + 3][h]);
    out[(size_t)(row0 + r) * COc + c] = osum / lsum;
  }
}

// ---------------------------------------------------------------------------
extern "C" void kernel_launch(void* const* d_in, const int* in_sizes, int n_in,
                              void* d_out, int out_size, void* d_ws, size_t ws_size,
                              hipStream_t stream) {
  const float* xq  = (const float*)d_in[0];
  const float* xk  = (const float*)d_in[1];
  const float* w1  = (const float*)d_in[2];
  const float* b1  = (const float*)d_in[3];
  const float* w2  = (const float*)d_in[4];
  const float* b2  = (const float*)d_in[5];
  const float* v1  = (const float*)d_in[6];
  const float* bv1 = (const float*)d_in[7];
  const float* v2  = (const float*)d_in[8];
  const float* bv2 = (const float*)d_in[9];
  float* out = (float*)d_out;

  const int BN = in_sizes[0] / Cc;  // B*N  = 2048
  const int BK = in_sizes[1] / Cc;  // B*Nk = 2048
  const int B = 2;                  // fixed by setup_inputs
  const int N = BN / B;
  const int Nk = BK / B;

  float* ws = (float*)d_ws;
  float* aW = ws;                              // BN*32
  float* aV = aW + (size_t)BN * CPWc;          // BN*16
  float* cP = aV + (size_t)BN * COc;           // BK*48 (packed tiles)
  ushort* w2f = (ushort*)(cP + (size_t)BK * 48);  // 64*8 ushort
  ushort* v2f = w2f + 64 * 8;                     // 64*8 ushort

  const int totalRows = BN + BK;
  const int nRowBlocks = (totalRows + 63) / 64;   // 4 threads per row
  ppa_precompute<<<nRowBlocks + 1, NTH, 0, stream>>>(
      xq, xk, w1, b1, v1, bv1, w2, v2,
      aW, aV, cP, w2f, v2f, BN, BK, Nk, nRowBlocks);
  ppa_main_mfma<<<BN / 2, MTH, 0, stream>>>(aW, aV, cP, w2f, b2, v2f, bv2,
                                            out, N, Nk);
}

// Round 14
// 25.723 us; speedup vs baseline: 1.7014x; 1.1776x over previous
//
#include <hip/hip_runtime.h>
#include <hip/hip_bf16.h>
#include <math.h>

// Problem constants (fixed by setup_inputs)
static constexpr int Cc   = 16;   // C
static constexpr int COc  = 16;   // CO
static constexpr int Hh   = 4;    // heads
static constexpr int CPWc = 32;   // 2*C
static constexpr int NTH  = 256;  // precompute block size
static constexpr int MTH  = 512;  // main block size (8 waves, 2 rows)
static constexpr int TFH  = 768;  // f16 elements per packed 16-k tile (1.5 KB)

typedef _Float16 f16x2 __attribute__((ext_vector_type(2)));
typedef _Float16 f16x8 __attribute__((ext_vector_type(8)));   // 4 VGPR
typedef __attribute__((ext_vector_type(4))) float f32x4v;     // MFMA C/D

union F4 { float4 v; float f[4]; };
// f16 octet with fully NAMED pair members (no ext_vector arrays -> no
// scratch demotion; r3 lesson).
union H8 {
  f16x8 v8;
  struct { f16x2 q0, q1, q2, q3; } p;
  float4 f4;
};

__device__ __forceinline__ ushort f2h(float x) {
  _Float16 h = (_Float16)x;
  ushort u;
  __builtin_memcpy(&u, &h, 2);
  return u;
}
__device__ __forceinline__ f16x2 relu2(f16x2 x) {
  return __builtin_elementwise_max(x, (f16x2)(_Float16)0);
}

// ---------------------------------------------------------------------------
// Kernel 1: per-row first-layer projections (fp32 math, validated r1-r13),
// 4 threads per row; cP now stored in F16 (r14: halves tile bytes AND
// enables pk-f16 fragment math in the main kernel).
// cP f16 layout per 16-k tile (768 f16 = 1.5 KB):
//   [  0,512): lane l=g*16+m -> cW[k=T*16+m][g*8 .. g*8+8) as 8 f16 (16B)
//   [512,768): lane l&31     -> cV[k][gg*8 .. gg*8+8)      (gg = (l>>4)&1)
// Pack block (nRowBlocks): w2f REPLICATED cols B[k][n] = w2[k][n>>2]
// (r14: logits D then lands on the lane that needs it -> no shfl);
// v2f = 0.5*v2 duplicated into both K-halves (A duplicates hv -> exact).
// ---------------------------------------------------------------------------
__global__ __launch_bounds__(NTH) void ppa_precompute(
    const float* __restrict__ xq, const float* __restrict__ xk,
    const float* __restrict__ w1, const float* __restrict__ b1,
    const float* __restrict__ v1, const float* __restrict__ bv1,
    const float* __restrict__ w2, const float* __restrict__ v2,
    float* __restrict__ aW, float* __restrict__ aV,
    ushort* __restrict__ cP,
    ushort* __restrict__ w2f, ushort* __restrict__ v2f,
    int BN, int BK, int Nk, int nRowBlocks) {
  const int t = threadIdx.x;

  if (blockIdx.x == nRowBlocks) {  // packing block
    if (t < 64) {
      const int n = t & 15, g = t >> 4;
#pragma unroll
      for (int i = 0; i < 8; ++i) {
        const int k = g * 8 + i;
        w2f[t * 8 + i] = f2h(w2[k * Hh + (n >> 2)]);       // replicated cols
        v2f[t * 8 + i] = f2h(0.5f * v2[(k & 15) * COc + n]);
      }
    }
    return;
  }

  __shared__ float sw1[CPWc * CPWc];
  __shared__ float sv1[CPWc * COc];
  __shared__ float sb1[CPWc];
  __shared__ float sbv1[COc];
  for (int i = t; i < CPWc * CPWc; i += NTH) sw1[i] = w1[i];
  for (int i = t; i < CPWc * COc; i += NTH) sv1[i] = v1[i];
  if (t < CPWc) sb1[t] = b1[t];
  if (t < COc) sbv1[t] = bv1[t];
  __syncthreads();

  const int r = blockIdx.x * 64 + (t >> 2);
  const int sub = t & 3;
  if (r >= BN + BK) return;
  const bool isQ = (r < BN);
  const int rr = isQ ? r : (r - BN);
  const float* src = isQ ? (xq + (size_t)rr * Cc) : (xk + (size_t)rr * Cc);

  float x[Cc];
#pragma unroll
  for (int i = 0; i < Cc; i += 4) {
    float4 v = *reinterpret_cast<const float4*>(src + i);
    x[i] = v.x; x[i + 1] = v.y; x[i + 2] = v.z; x[i + 3] = v.w;
  }

  if (isQ) {
    F4 o0, o1, ov;
#pragma unroll
    for (int jj = 0; jj < 8; ++jj) {
      const int j = sub * 8 + jj;
      float acc = sb1[j];
#pragma unroll
      for (int i = 0; i < Cc; ++i)
        acc += x[i] * (sw1[i * CPWc + j] - sw1[(i + Cc) * CPWc + j]);
      if (jj < 4) o0.f[jj] = acc; else o1.f[jj - 4] = acc;
    }
#pragma unroll
    for (int jj = 0; jj < 4; ++jj) {
      const int j = sub * 4 + jj;
      float acc = sbv1[j];
#pragma unroll
      for (int i = 0; i < Cc; ++i)
        acc += x[i] * (sv1[i * COc + j] - sv1[(i + Cc) * COc + j]);
      ov.f[jj] = acc;
    }
    float* ap = aW + (size_t)rr * CPWc + sub * 8;
    *reinterpret_cast<float4*>(ap) = o0.v;
    *reinterpret_cast<float4*>(ap + 4) = o1.v;
    *reinterpret_cast<float4*>(aV + (size_t)rr * COc + sub * 4) = ov.v;
  } else {
    float cw[8];
    float cv4[4];
#pragma unroll
    for (int jj = 0; jj < 8; ++jj) {
      const int j = sub * 8 + jj;
      float acc = 0.f;
#pragma unroll
      for (int i = 0; i < Cc; ++i) acc += x[i] * sw1[(i + Cc) * CPWc + j];
      cw[jj] = acc;
    }
#pragma unroll
    for (int jj = 0; jj < 4; ++jj) {
      const int j = sub * 4 + jj;
      float acc = 0.f;
#pragma unroll
      for (int i = 0; i < Cc; ++i) acc += x[i] * sv1[(i + Cc) * COc + j];
      cv4[jj] = acc;
    }
    const int bb = rr / Nk;
    const int kk = rr - bb * Nk;
    const int T = kk >> 4, mm = kk & 15;
    ushort* tp = cP + ((size_t)bb * (Nk >> 4) + T) * TFH;
    // cW octet (g == sub): 8 f16 = two 8B stores.
    ushort4 h0, h1;
    h0.x = f2h(cw[0]); h0.y = f2h(cw[1]); h0.z = f2h(cw[2]); h0.w = f2h(cw[3]);
    h1.x = f2h(cw[4]); h1.y = f2h(cw[5]); h1.z = f2h(cw[6]); h1.w = f2h(cw[7]);
    ushort* wp = tp + (sub * 16 + mm) * 8;
    *reinterpret_cast<ushort4*>(wp) = h0;
    *reinterpret_cast<ushort4*>(wp + 4) = h1;
    // cV quad: j in [sub*4, sub*4+4) -> gg = sub>>1, half = sub&1.
    ushort4 hv;
    hv.x = f2h(cv4[0]); hv.y = f2h(cv4[1]); hv.z = f2h(cv4[2]); hv.w = f2h(cv4[3]);
    const int gg = sub >> 1, half = sub & 1;
    *reinterpret_cast<ushort4*>(tp + 512 + (gg * 16 + mm) * 8 + half * 4) = hv;
  }
}

// ---------------------------------------------------------------------------
// Kernel 2 (MFMA, f16): one block per TWO consecutive rows, 512 threads =
// 8 waves; wave w: row = row0+(w>>2), k-quarter q = w&3; waves w and w+4
// read the same tiles -> L1 hit for the second reader (validated r13).
// R14: cP in f16 -> 2 loads/tile (was 4), pk-f16 fragment build (4 pk_add
// + 4 pk_max, no cvt), and REPLICATED w2 cols -> logits D already on the
// consuming lane (p == q, no shfl). Bias-in-C, l-accum on m&3==0, xor-16/32
// + cross-wave LDS reduction: validated r8-r13. Plain exp-sum softmax
// (logits ReLU'd >= 0). No launch-bounds cap (r2-r7 law: cap -> spill).
// ---------------------------------------------------------------------------
__global__ __launch_bounds__(MTH) void ppa_main_mfma(
    const float* __restrict__ aW, const float* __restrict__ aV,
    const ushort* __restrict__ cP,
    const ushort* __restrict__ w2f, const float* __restrict__ b2,
    const ushort* __restrict__ v2f, const float* __restrict__ bv2,
    float* __restrict__ out, int N, int Nk) {
  __shared__ float sro[8][COc];
  __shared__ float srl[8][Hh];

  const int t = threadIdx.x;
  const int lane = t & 63, w = t >> 6;
  const int q = w & 3;        // k-quarter
  const int m = lane & 15;
  const int g = lane >> 4;
  const int gg = g & 1;
  const int l31 = lane & 31;
  const int hh = m >> 2;
  const int row0 = blockIdx.x * 2;
  const int row = row0 + (w >> 2);
  const int b = row0 / N;     // both rows in same batch (N even)

  // Loop-invariant per-lane data, converted once to f16 pairs.
  f16x2 a01, a23, a45, a67, av01, av23, av45, av67;
  {
    const float* aRow = aW + (size_t)row * CPWc + g * 8;
    F4 v0, v1;
    v0.v = *reinterpret_cast<const float4*>(aRow);
    v1.v = *reinterpret_cast<const float4*>(aRow + 4);
    a01 = f16x2{(_Float16)v0.f[0], (_Float16)v0.f[1]};
    a23 = f16x2{(_Float16)v0.f[2], (_Float16)v0.f[3]};
    a45 = f16x2{(_Float16)v1.f[0], (_Float16)v1.f[1]};
    a67 = f16x2{(_Float16)v1.f[2], (_Float16)v1.f[3]};
    const float* avRow = aV + (size_t)row * COc + gg * 8;
    F4 u0, u1;
    u0.v = *reinterpret_cast<const float4*>(avRow);
    u1.v = *reinterpret_cast<const float4*>(avRow + 4);
    av01 = f16x2{(_Float16)u0.f[0], (_Float16)u0.f[1]};
    av23 = f16x2{(_Float16)u0.f[2], (_Float16)u0.f[3]};
    av45 = f16x2{(_Float16)u1.f[0], (_Float16)u1.f[1]};
    av67 = f16x2{(_Float16)u1.f[2], (_Float16)u1.f[3]};
  }
  const f16x8 wfrag = *reinterpret_cast<const f16x8*>(w2f + lane * 8);
  const f16x8 vfrag = *reinterpret_cast<const f16x8*>(v2f + lane * 8);
  const float b2h = b2[hh];
  const float bv2c = bv2[m];
  const f32x4v cbW = {b2h, b2h, b2h, b2h};
  const f32x4v cbV = {bv2c, bv2c, bv2c, bv2c};

  float o_acc = 0.f, l_acc = 0.f;

  // Wave's packed tile base: tiles T = q*16 + s.
  const ushort* tb = cP + ((size_t)b * (Nk >> 4) + (size_t)q * 16) * TFH;

  // ---- software pipeline: prefetch tile s+1 while processing tile s.
  H8 cw, cv;
  cw.f4 = *reinterpret_cast<const float4*>(tb + lane * 8);
  cv.f4 = *reinterpret_cast<const float4*>(tb + 512 + l31 * 8);

#pragma unroll
  for (int s = 0; s < 16; ++s) {
    H8 nw, nv;
    nw.f4 = float4{0.f, 0.f, 0.f, 0.f};
    nv.f4 = float4{0.f, 0.f, 0.f, 0.f};
    if (s < 15) {
      const ushort* nb = tb + (size_t)(s + 1) * TFH;
      nw.f4 = *reinterpret_cast<const float4*>(nb + lane * 8);
      nv.f4 = *reinterpret_cast<const float4*>(nb + 512 + l31 * 8);
    }

    // ---- logits tile: A = hw = relu(a + cW) (pk-f16); C = b2 (replicated
    //      w2 cols: D[r] = logits[k=g*4+r][head m>>2] -> p needs no shfl).
    H8 fw;
    fw.p.q0 = relu2(a01 + cw.p.q0);
    fw.p.q1 = relu2(a23 + cw.p.q1);
    fw.p.q2 = relu2(a45 + cw.p.q2);
    fw.p.q3 = relu2(a67 + cw.p.q3);
    const f32x4v lgD =
        __builtin_amdgcn_mfma_f32_16x16x32_f16(fw.v8, wfrag, cbW, 0, 0, 0);

    const float p0 = __expf(fmaxf(lgD[0], 0.f));
    const float p1 = __expf(fmaxf(lgD[1], 0.f));
    const float p2 = __expf(fmaxf(lgD[2], 0.f));
    const float p3 = __expf(fmaxf(lgD[3], 0.f));
    if ((m & 3) == 0) l_acc += (p0 + p1) + (p2 + p3);

    // ---- val tile: A = hv duplicated into both K-halves (v2f = 0.5*v2 in
    //      both halves -> exact); C = bv2.
    H8 fv;
    fv.p.q0 = relu2(av01 + cv.p.q0);
    fv.p.q1 = relu2(av23 + cv.p.q1);
    fv.p.q2 = relu2(av45 + cv.p.q2);
    fv.p.q3 = relu2(av67 + cv.p.q3);
    const f32x4v vD =
        __builtin_amdgcn_mfma_f32_16x16x32_f16(fv.v8, vfrag, cbV, 0, 0, 0);

    o_acc += p0 * fmaxf(vD[0], 0.f);
    o_acc += p1 * fmaxf(vD[1], 0.f);
    o_acc += p2 * fmaxf(vD[2], 0.f);
    o_acc += p3 * fmaxf(vD[3], 0.f);

    cw = nw; cv = nv;
  }

  // ---- reduce over g-groups (xor 16/32 preserves m), then across waves.
  o_acc += __shfl_xor(o_acc, 16);
  o_acc += __shfl_xor(o_acc, 32);
  l_acc += __shfl_xor(l_acc, 16);
  l_acc += __shfl_xor(l_acc, 32);
  if (lane < COc) sro[w][m] = o_acc;
  if (lane < COc && (lane & 3) == 0) srl[w][lane >> 2] = l_acc;
  __syncthreads();

  if (t < 2 * COc) {
    const int r = t >> 4, c = t & 15, h = c >> 2;
    const int wb = r * 4;
    const float osum = (sro[wb][c] + sro[wb + 1][c]) +
                       (sro[wb + 2][c] + sro[wb + 3][c]);
    const float lsum = (srl[wb][h] + srl[wb + 1][h]) +
                       (srl[wb + 2][h] + srl[wb + 3][h]);
    out[(size_t)(row0 + r) * COc + c] = osum / lsum;
  }
}

// ---------------------------------------------------------------------------
extern "C" void kernel_launch(void* const* d_in, const int* in_sizes, int n_in,
                              void* d_out, int out_size, void* d_ws, size_t ws_size,
                              hipStream_t stream) {
  const float* xq  = (const float*)d_in[0];
  const float* xk  = (const float*)d_in[1];
  const float* w1  = (const float*)d_in[2];
  const float* b1  = (const float*)d_in[3];
  const float* w2  = (const float*)d_in[4];
  const float* b2  = (const float*)d_in[5];
  const float* v1  = (const float*)d_in[6];
  const float* bv1 = (const float*)d_in[7];
  const float* v2  = (const float*)d_in[8];
  const float* bv2 = (const float*)d_in[9];
  float* out = (float*)d_out;

  const int BN = in_sizes[0] / Cc;  // B*N  = 2048
  const int BK = in_sizes[1] / Cc;  // B*Nk = 2048
  const int B = 2;                  // fixed by setup_inputs
  const int N = BN / B;
  const int Nk = BK / B;

  float* ws = (float*)d_ws;
  float* aW = ws;                              // BN*32 f32
  float* aV = aW + (size_t)BN * CPWc;          // BN*16 f32
  ushort* cP = (ushort*)(aV + (size_t)BN * COc);  // BK*48 f16 (packed tiles)
  ushort* w2f = cP + (size_t)BK * 48;             // 64*8 f16
  ushort* v2f = w2f + 64 * 8;                     // 64*8 f16

  const int totalRows = BN + BK;
  const int nRowBlocks = (totalRows + 63) / 64;   // 4 threads per row
  ppa_precompute<<<nRowBlocks + 1, NTH, 0, stream>>>(
      xq, xk, w1, b1, v1, bv1, w2, v2,
      aW, aV, cP, w2f, v2f, BN, BK, Nk, nRowBlocks);
  ppa_main_mfma<<<BN / 2, MTH, 0, stream>>>(aW, aV, cP, w2f, b2, v2f, bv2,
                                            out, N, Nk);
}

// Round 15
// 25.442 us; speedup vs baseline: 1.7202x; 1.0110x over previous
//
#include <hip/hip_runtime.h>
#include <hip/hip_bf16.h>
#include <math.h>

// Problem constants (fixed by setup_inputs)
static constexpr int Cc   = 16;   // C
static constexpr int COc  = 16;   // CO
static constexpr int Hh   = 4;    // heads
static constexpr int CPWc = 32;   // 2*C
static constexpr int NTH  = 256;  // precompute block size
static constexpr int MTH  = 512;  // main block size (8 waves, 2 rows)
static constexpr int TFH  = 768;  // f16 elements per packed 16-k tile (1.5 KB)

typedef _Float16 f16x2 __attribute__((ext_vector_type(2)));
typedef _Float16 f16x8 __attribute__((ext_vector_type(8)));   // 4 VGPR
typedef __attribute__((ext_vector_type(4))) float f32x4v;     // MFMA C/D

union F4 { float4 v; float f[4]; };
// f16 octet with fully NAMED pair members (no ext_vector arrays -> no
// scratch demotion; r3 lesson).
union H8 {
  f16x8 v8;
  struct { f16x2 q0, q1, q2, q3; } p;
  float4 f4;
};

__device__ __forceinline__ ushort f2h(float x) {
  _Float16 h = (_Float16)x;
  ushort u;
  __builtin_memcpy(&u, &h, 2);
  return u;
}
__device__ __forceinline__ f16x2 relu2(f16x2 x) {
  return __builtin_elementwise_max(x, (f16x2)(_Float16)0);
}

// ---------------------------------------------------------------------------
// Kernel 1: per-row first-layer projections (fp32 math, validated r1-r14),
// 4 threads per row; cP stored in F16 (validated r14).
// cP f16 layout per 16-k tile (768 f16 = 1.5 KB):
//   [  0,512): lane l=g*16+m -> cW[k=T*16+m][g*8 .. g*8+8) as 8 f16 (16B)
//   [512,768): lane l&31     -> cV[k][gg*8 .. gg*8+8)      (gg = (l>>4)&1)
// Pack block (nRowBlocks): w2f REPLICATED cols B[k][n] = w2[k][n>>2]
// (logits D lands on its consuming lane -> no shfl; validated r14);
// v2f = 0.5*v2 duplicated into both K-halves (A duplicates hv -> exact).
// ---------------------------------------------------------------------------
__global__ __launch_bounds__(NTH) void ppa_precompute(
    const float* __restrict__ xq, const float* __restrict__ xk,
    const float* __restrict__ w1, const float* __restrict__ b1,
    const float* __restrict__ v1, const float* __restrict__ bv1,
    const float* __restrict__ w2, const float* __restrict__ v2,
    float* __restrict__ aW, float* __restrict__ aV,
    ushort* __restrict__ cP,
    ushort* __restrict__ w2f, ushort* __restrict__ v2f,
    int BN, int BK, int Nk, int nRowBlocks) {
  const int t = threadIdx.x;

  if (blockIdx.x == nRowBlocks) {  // packing block
    if (t < 64) {
      const int n = t & 15, g = t >> 4;
#pragma unroll
      for (int i = 0; i < 8; ++i) {
        const int k = g * 8 + i;
        w2f[t * 8 + i] = f2h(w2[k * Hh + (n >> 2)]);       // replicated cols
        v2f[t * 8 + i] = f2h(0.5f * v2[(k & 15) * COc + n]);
      }
    }
    return;
  }

  __shared__ float sw1[CPWc * CPWc];
  __shared__ float sv1[CPWc * COc];
  __shared__ float sb1[CPWc];
  __shared__ float sbv1[COc];
  for (int i = t; i < CPWc * CPWc; i += NTH) sw1[i] = w1[i];
  for (int i = t; i < CPWc * COc; i += NTH) sv1[i] = v1[i];
  if (t < CPWc) sb1[t] = b1[t];
  if (t < COc) sbv1[t] = bv1[t];
  __syncthreads();

  const int r = blockIdx.x * 64 + (t >> 2);
  const int sub = t & 3;
  if (r >= BN + BK) return;
  const bool isQ = (r < BN);
  const int rr = isQ ? r : (r - BN);
  const float* src = isQ ? (xq + (size_t)rr * Cc) : (xk + (size_t)rr * Cc);

  float x[Cc];
#pragma unroll
  for (int i = 0; i < Cc; i += 4) {
    float4 v = *reinterpret_cast<const float4*>(src + i);
    x[i] = v.x; x[i + 1] = v.y; x[i + 2] = v.z; x[i + 3] = v.w;
  }

  if (isQ) {
    F4 o0, o1, ov;
#pragma unroll
    for (int jj = 0; jj < 8; ++jj) {
      const int j = sub * 8 + jj;
      float acc = sb1[j];
#pragma unroll
      for (int i = 0; i < Cc; ++i)
        acc += x[i] * (sw1[i * CPWc + j] - sw1[(i + Cc) * CPWc + j]);
      if (jj < 4) o0.f[jj] = acc; else o1.f[jj - 4] = acc;
    }
#pragma unroll
    for (int jj = 0; jj < 4; ++jj) {
      const int j = sub * 4 + jj;
      float acc = sbv1[j];
#pragma unroll
      for (int i = 0; i < Cc; ++i)
        acc += x[i] * (sv1[i * COc + j] - sv1[(i + Cc) * COc + j]);
      ov.f[jj] = acc;
    }
    float* ap = aW + (size_t)rr * CPWc + sub * 8;
    *reinterpret_cast<float4*>(ap) = o0.v;
    *reinterpret_cast<float4*>(ap + 4) = o1.v;
    *reinterpret_cast<float4*>(aV + (size_t)rr * COc + sub * 4) = ov.v;
  } else {
    float cw[8];
    float cv4[4];
#pragma unroll
    for (int jj = 0; jj < 8; ++jj) {
      const int j = sub * 8 + jj;
      float acc = 0.f;
#pragma unroll
      for (int i = 0; i < Cc; ++i) acc += x[i] * sw1[(i + Cc) * CPWc + j];
      cw[jj] = acc;
    }
#pragma unroll
    for (int jj = 0; jj < 4; ++jj) {
      const int j = sub * 4 + jj;
      float acc = 0.f;
#pragma unroll
      for (int i = 0; i < Cc; ++i) acc += x[i] * sv1[(i + Cc) * COc + j];
      cv4[jj] = acc;
    }
    const int bb = rr / Nk;
    const int kk = rr - bb * Nk;
    const int T = kk >> 4, mm = kk & 15;
    ushort* tp = cP + ((size_t)bb * (Nk >> 4) + T) * TFH;
    // cW octet (g == sub): 8 f16 = two 8B stores.
    ushort4 h0, h1;
    h0.x = f2h(cw[0]); h0.y = f2h(cw[1]); h0.z = f2h(cw[2]); h0.w = f2h(cw[3]);
    h1.x = f2h(cw[4]); h1.y = f2h(cw[5]); h1.z = f2h(cw[6]); h1.w = f2h(cw[7]);
    ushort* wp = tp + (sub * 16 + mm) * 8;
    *reinterpret_cast<ushort4*>(wp) = h0;
    *reinterpret_cast<ushort4*>(wp + 4) = h1;
    // cV quad: j in [sub*4, sub*4+4) -> gg = sub>>1, half = sub&1.
    ushort4 hv;
    hv.x = f2h(cv4[0]); hv.y = f2h(cv4[1]); hv.z = f2h(cv4[2]); hv.w = f2h(cv4[3]);
    const int gg = sub >> 1, half = sub & 1;
    *reinterpret_cast<ushort4*>(tp + 512 + (gg * 16 + mm) * 8 + half * 4) = hv;
  }
}

// ---------------------------------------------------------------------------
// Kernel 2 (MFMA, f16): one block per TWO consecutive rows, 512 threads =
// 8 waves. R15 re-split: wave w handles BOTH rows over HALF its k-quarter
// (8 tiles): q = w&3, half = w>>2. Each tile load now feeds 2 rows'
// fragments -> load instructions / L1 line-issue HALVE (the r14 model put
// L1 issue at ~5us vs ~2.7us VALU: loads were the bound). Unlike r12's
// failed 2-row variant: f16 state is small (+16 VGPR), grid/occupancy
// unchanged, per-wave tile count halves so VALU total is constant.
// Fragment math, replicated-w2 (no shfl), bias-in-C, l-accum on m&3==0:
// validated r8-r14. Plain exp-sum softmax (logits ReLU'd >= 0).
// No launch-bounds cap (r2-r7 law: cap -> spill).
// ---------------------------------------------------------------------------
__global__ __launch_bounds__(MTH) void ppa_main_mfma(
    const float* __restrict__ aW, const float* __restrict__ aV,
    const ushort* __restrict__ cP,
    const ushort* __restrict__ w2f, const float* __restrict__ b2,
    const ushort* __restrict__ v2f, const float* __restrict__ bv2,
    float* __restrict__ out, int N, int Nk) {
  __shared__ float sro[8][2][COc];
  __shared__ float srl[8][2][Hh];

  const int t = threadIdx.x;
  const int lane = t & 63, w = t >> 6;
  const int q = w & 3;        // k-quarter
  const int half = w >> 2;    // half of the quarter (tiles 0-7 / 8-15)
  const int m = lane & 15;
  const int g = lane >> 4;
  const int gg = g & 1;
  const int l31 = lane & 31;
  const int hh = m >> 2;
  const int row0 = blockIdx.x * 2;
  const int b = row0 / N;     // both rows in same batch (N even)

  // Loop-invariant per-lane data for BOTH rows, converted once to f16.
  f16x2 a0_0, a0_1, a0_2, a0_3, av0_0, av0_1, av0_2, av0_3;
  f16x2 a1_0, a1_1, a1_2, a1_3, av1_0, av1_1, av1_2, av1_3;
  {
    const float* aR0 = aW + (size_t)row0 * CPWc + g * 8;
    const float* aR1 = aW + (size_t)(row0 + 1) * CPWc + g * 8;
    F4 v0, v1, u0, u1;
    v0.v = *reinterpret_cast<const float4*>(aR0);
    v1.v = *reinterpret_cast<const float4*>(aR0 + 4);
    u0.v = *reinterpret_cast<const float4*>(aR1);
    u1.v = *reinterpret_cast<const float4*>(aR1 + 4);
    a0_0 = f16x2{(_Float16)v0.f[0], (_Float16)v0.f[1]};
    a0_1 = f16x2{(_Float16)v0.f[2], (_Float16)v0.f[3]};
    a0_2 = f16x2{(_Float16)v1.f[0], (_Float16)v1.f[1]};
    a0_3 = f16x2{(_Float16)v1.f[2], (_Float16)v1.f[3]};
    a1_0 = f16x2{(_Float16)u0.f[0], (_Float16)u0.f[1]};
    a1_1 = f16x2{(_Float16)u0.f[2], (_Float16)u0.f[3]};
    a1_2 = f16x2{(_Float16)u1.f[0], (_Float16)u1.f[1]};
    a1_3 = f16x2{(_Float16)u1.f[2], (_Float16)u1.f[3]};
    const float* vR0 = aV + (size_t)row0 * COc + gg * 8;
    const float* vR1 = aV + (size_t)(row0 + 1) * COc + gg * 8;
    F4 w0, w1v, x0, x1;
    w0.v = *reinterpret_cast<const float4*>(vR0);
    w1v.v = *reinterpret_cast<const float4*>(vR0 + 4);
    x0.v = *reinterpret_cast<const float4*>(vR1);
    x1.v = *reinterpret_cast<const float4*>(vR1 + 4);
    av0_0 = f16x2{(_Float16)w0.f[0], (_Float16)w0.f[1]};
    av0_1 = f16x2{(_Float16)w0.f[2], (_Float16)w0.f[3]};
    av0_2 = f16x2{(_Float16)w1v.f[0], (_Float16)w1v.f[1]};
    av0_3 = f16x2{(_Float16)w1v.f[2], (_Float16)w1v.f[3]};
    av1_0 = f16x2{(_Float16)x0.f[0], (_Float16)x0.f[1]};
    av1_1 = f16x2{(_Float16)x0.f[2], (_Float16)x0.f[3]};
    av1_2 = f16x2{(_Float16)x1.f[0], (_Float16)x1.f[1]};
    av1_3 = f16x2{(_Float16)x1.f[2], (_Float16)x1.f[3]};
  }
  const f16x8 wfrag = *reinterpret_cast<const f16x8*>(w2f + lane * 8);
  const f16x8 vfrag = *reinterpret_cast<const f16x8*>(v2f + lane * 8);
  const float b2h = b2[hh];
  const float bv2c = bv2[m];
  const f32x4v cbW = {b2h, b2h, b2h, b2h};
  const f32x4v cbV = {bv2c, bv2c, bv2c, bv2c};

  float o0 = 0.f, l0 = 0.f, o1 = 0.f, l1 = 0.f;

  // Wave's packed tile base: tiles T = q*16 + half*8 + s, s in [0,8).
  const ushort* tb =
      cP + ((size_t)b * (Nk >> 4) + (size_t)q * 16 + (size_t)half * 8) * TFH;

  // ---- software pipeline: prefetch tile s+1 while processing tile s.
  H8 cw, cv;
  cw.f4 = *reinterpret_cast<const float4*>(tb + lane * 8);
  cv.f4 = *reinterpret_cast<const float4*>(tb + 512 + l31 * 8);

#pragma unroll
  for (int s = 0; s < 8; ++s) {
    H8 nw, nv;
    nw.f4 = float4{0.f, 0.f, 0.f, 0.f};
    nv.f4 = float4{0.f, 0.f, 0.f, 0.f};
    if (s < 7) {
      const ushort* nb = tb + (size_t)(s + 1) * TFH;
      nw.f4 = *reinterpret_cast<const float4*>(nb + lane * 8);
      nv.f4 = *reinterpret_cast<const float4*>(nb + 512 + l31 * 8);
    }

    // ---- logits, row 0 and row 1 (shared cw).
    H8 fw0, fw1;
    fw0.p.q0 = relu2(a0_0 + cw.p.q0);
    fw0.p.q1 = relu2(a0_1 + cw.p.q1);
    fw0.p.q2 = relu2(a0_2 + cw.p.q2);
    fw0.p.q3 = relu2(a0_3 + cw.p.q3);
    const f32x4v lg0 =
        __builtin_amdgcn_mfma_f32_16x16x32_f16(fw0.v8, wfrag, cbW, 0, 0, 0);
    fw1.p.q0 = relu2(a1_0 + cw.p.q0);
    fw1.p.q1 = relu2(a1_1 + cw.p.q1);
    fw1.p.q2 = relu2(a1_2 + cw.p.q2);
    fw1.p.q3 = relu2(a1_3 + cw.p.q3);
    const f32x4v lg1 =
        __builtin_amdgcn_mfma_f32_16x16x32_f16(fw1.v8, wfrag, cbW, 0, 0, 0);

    const float p00 = __expf(fmaxf(lg0[0], 0.f));
    const float p01 = __expf(fmaxf(lg0[1], 0.f));
    const float p02 = __expf(fmaxf(lg0[2], 0.f));
    const float p03 = __expf(fmaxf(lg0[3], 0.f));
    const float p10 = __expf(fmaxf(lg1[0], 0.f));
    const float p11 = __expf(fmaxf(lg1[1], 0.f));
    const float p12 = __expf(fmaxf(lg1[2], 0.f));
    const float p13 = __expf(fmaxf(lg1[3], 0.f));
    if ((m & 3) == 0) {
      l0 += (p00 + p01) + (p02 + p03);
      l1 += (p10 + p11) + (p12 + p13);
    }

    // ---- values, row 0 and row 1 (shared cv; v2f = 0.5*v2 in both
    //      K-halves, A duplicates hv -> exact).
    H8 fv0, fv1;
    fv0.p.q0 = relu2(av0_0 + cv.p.q0);
    fv0.p.q1 = relu2(av0_1 + cv.p.q1);
    fv0.p.q2 = relu2(av0_2 + cv.p.q2);
    fv0.p.q3 = relu2(av0_3 + cv.p.q3);
    const f32x4v vD0 =
        __builtin_amdgcn_mfma_f32_16x16x32_f16(fv0.v8, vfrag, cbV, 0, 0, 0);
    fv1.p.q0 = relu2(av1_0 + cv.p.q0);
    fv1.p.q1 = relu2(av1_1 + cv.p.q1);
    fv1.p.q2 = relu2(av1_2 + cv.p.q2);
    fv1.p.q3 = relu2(av1_3 + cv.p.q3);
    const f32x4v vD1 =
        __builtin_amdgcn_mfma_f32_16x16x32_f16(fv1.v8, vfrag, cbV, 0, 0, 0);

    o0 += p00 * fmaxf(vD0[0], 0.f);
    o0 += p01 * fmaxf(vD0[1], 0.f);
    o0 += p02 * fmaxf(vD0[2], 0.f);
    o0 += p03 * fmaxf(vD0[3], 0.f);
    o1 += p10 * fmaxf(vD1[0], 0.f);
    o1 += p11 * fmaxf(vD1[1], 0.f);
    o1 += p12 * fmaxf(vD1[2], 0.f);
    o1 += p13 * fmaxf(vD1[3], 0.f);

    cw = nw; cv = nv;
  }

  // ---- reduce over g-groups (xor 16/32 preserves m), then across waves.
  o0 += __shfl_xor(o0, 16);
  o0 += __shfl_xor(o0, 32);
  o1 += __shfl_xor(o1, 16);
  o1 += __shfl_xor(o1, 32);
  l0 += __shfl_xor(l0, 16);
  l0 += __shfl_xor(l0, 32);
  l1 += __shfl_xor(l1, 16);
  l1 += __shfl_xor(l1, 32);
  if (lane < COc) { sro[w][0][m] = o0; sro[w][1][m] = o1; }
  if (lane < COc && (lane & 3) == 0) {
    srl[w][0][lane >> 2] = l0;
    srl[w][1][lane >> 2] = l1;
  }
  __syncthreads();

  if (t < 2 * COc) {
    const int r = t >> 4, c = t & 15, h = c >> 2;
    float osum = 0.f, lsum = 0.f;
#pragma unroll
    for (int ww = 0; ww < 8; ++ww) {
      osum += sro[ww][r][c];
      lsum += srl[ww][r][h];
    }
    out[(size_t)(row0 + r) * COc + c] = osum / lsum;
  }
}

// ---------------------------------------------------------------------------
extern "C" void kernel_launch(void* const* d_in, const int* in_sizes, int n_in,
                              void* d_out, int out_size, void* d_ws, size_t ws_size,
                              hipStream_t stream) {
  const float* xq  = (const float*)d_in[0];
  const float* xk  = (const float*)d_in[1];
  const float* w1  = (const float*)d_in[2];
  const float* b1  = (const float*)d_in[3];
  const float* w2  = (const float*)d_in[4];
  const float* b2  = (const float*)d_in[5];
  const float* v1  = (const float*)d_in[6];
  const float* bv1 = (const float*)d_in[7];
  const float* v2  = (const float*)d_in[8];
  const float* bv2 = (const float*)d_in[9];
  float* out = (float*)d_out;

  const int BN = in_sizes[0] / Cc;  // B*N  = 2048
  const int BK = in_sizes[1] / Cc;  // B*Nk = 2048
  const int B = 2;                  // fixed by setup_inputs
  const int N = BN / B;
  const int Nk = BK / B;

  float* ws = (float*)d_ws;
  float* aW = ws;                              // BN*32 f32
  float* aV = aW + (size_t)BN * CPWc;          // BN*16 f32
  ushort* cP = (ushort*)(aV + (size_t)BN * COc);  // BK*48 f16 (packed tiles)
  ushort* w2f = cP + (size_t)BK * 48;             // 64*8 f16
  ushort* v2f = w2f + 64 * 8;                     // 64*8 f16

  const int totalRows = BN + BK;
  const int nRowBlocks = (totalRows + 63) / 64;   // 4 threads per row
  ppa_precompute<<<nRowBlocks + 1, NTH, 0, stream>>>(
      xq, xk, w1, b1, v1, bv1, w2, v2,
      aW, aV, cP, w2f, v2f, BN, BK, Nk, nRowBlocks);
  ppa_main_mfma<<<BN / 2, MTH, 0, stream>>>(aW, aV, cP, w2f, b2, v2f, bv2,
                                            out, N, Nk);
}